// Round 1
// baseline (803.244 us; speedup 1.0000x reference)
//
#include <hip/hip_runtime.h>
#include <cstdint>

#define DEV __device__ __forceinline__

typedef __attribute__((ext_vector_type(4))) float f32x4;
typedef __attribute__((ext_vector_type(4))) float float4v;
typedef __attribute__((ext_vector_type(8))) short bf16x8;
typedef __attribute__((ext_vector_type(4))) unsigned short ushort4v;
typedef unsigned short u16;

static constexpr int Bb = 4, Tt = 2048, Hh = 16, KVh = 4, Dd = 128;

DEV u16 f2bf(float x) {
    union { float f; unsigned u; } v; v.f = x;
    unsigned r = v.u + 0x7FFF + ((v.u >> 16) & 1);
    return (u16)(r >> 16);
}
DEV float bf2f(u16 b) {
    union { unsigned u; float f; } v; v.u = ((unsigned)b) << 16;
    return v.f;
}

typedef const void __attribute__((address_space(1)))* gas1;
typedef void __attribute__((address_space(3)))* las3;
DEV void gload16(const void* g, void* l) {
    __builtin_amdgcn_global_load_lds((gas1)g, (las3)l, 16, 0, 0);
}

// ---------------- cast x -> bf16 ----------------
__global__ __launch_bounds__(256) void cast_k(const float* __restrict__ x, u16* __restrict__ xb, long n4) {
    long id = (long)blockIdx.x * 256 + threadIdx.x;
    if (id >= n4) return;
    float4v v = *(const float4v*)&x[id * 4];
    ushort4v o;
    o[0] = f2bf(v[0]); o[1] = f2bf(v[1]); o[2] = f2bf(v[2]); o[3] = f2bf(v[3]);
    *(ushort4v*)&xb[id * 4] = o;
}

// ---------------- transpose+cast weight: W (K x N) f32 -> Wt (N x K) bf16 ----------------
__global__ __launch_bounds__(256) void twt_k(const float* __restrict__ W, u16* __restrict__ Wt, int K, int N) {
    __shared__ float tile[32][33];
    int tx = threadIdx.x, ty = threadIdx.y;
    long n0 = (long)blockIdx.x * 32, k0 = (long)blockIdx.y * 32;
#pragma unroll
    for (int j = 0; j < 4; j++)
        tile[ty + j * 8][tx] = W[(k0 + ty + j * 8) * (long)N + n0 + tx];
    __syncthreads();
#pragma unroll
    for (int j = 0; j < 4; j++)
        Wt[(n0 + ty + j * 8) * (long)K + k0 + tx] = f2bf(tile[tx][ty + j * 8]);
}

// ---------------- transpose v (b,t,kv,d) -> vt (b,kv,d,t) ----------------
__global__ __launch_bounds__(256) void tv_k(const u16* __restrict__ v, u16* __restrict__ vt) {
    __shared__ u16 tile[32][33];
    int tx = threadIdx.x, ty = threadIdx.y;
    int d0 = blockIdx.x * 32;
    int t0 = blockIdx.y * 32;
    int bk = blockIdx.z;
    int b = bk >> 2, kv = bk & 3;
#pragma unroll
    for (int j = 0; j < 4; j++)
        tile[ty + j * 8][tx] = v[((long)(b * Tt + t0 + ty + j * 8) * KVh + kv) * Dd + d0 + tx];
    __syncthreads();
#pragma unroll
    for (int j = 0; j < 4; j++)
        vt[((long)(b * KVh + kv) * Dd + d0 + ty + j * 8) * Tt + t0 + tx] = tile[tx][ty + j * 8];
}

// ---------------- rope tables: [t][i], i<64 ----------------
__global__ __launch_bounds__(256) void tables_k(float* __restrict__ cosb, float* __restrict__ sinb) {
    int id = blockIdx.x * 256 + threadIdx.x; // < 2048*64
    int t = id >> 6, i = id & 63;
    float inv = powf(10000.0f, -(float)i * (1.0f / 64.0f));
    float f = (float)t * inv;
    cosb[id] = cosf(f);
    sinb[id] = sinf(f);
}

// ---------------- rope in-place on (b,t,nh,128); scale folded for q ----------------
__global__ __launch_bounds__(256) void rope_k(u16* __restrict__ p, const float* __restrict__ cosb,
                                              const float* __restrict__ sinb, int nh, float scale, int total) {
    int id = blockIdx.x * 256 + threadIdx.x;
    if (id >= total) return;
    int i = id & 63;
    int bth = id >> 6;
    int t = (bth / nh) % Tt;
    u16* ptr = p + (long)bth * Dd;
    float x1 = bf2f(ptr[i]), x2 = bf2f(ptr[i + 64]);
    float c = cosb[t * 64 + i], s = sinb[t * 64 + i];
    ptr[i] = f2bf((x1 * c - x2 * s) * scale);
    ptr[i + 64] = f2bf((x2 * c + x1 * s) * scale);
}

// ---------------- GEMM: A (M x K) bf16 row-major, Bt (N x K) bf16 row-major -> C (M x N) ----------------
template <int F32OUT>
__global__ __launch_bounds__(256) void gemm_k(const u16* __restrict__ A, const u16* __restrict__ Bt,
                                              void* __restrict__ Cout, int M, int N, int K) {
    __shared__ u16 aLds[128 * 32];
    __shared__ u16 bLds[128 * 32];
    const int tid = threadIdx.x;
    const int lane = tid & 63;
    const int wid = __builtin_amdgcn_readfirstlane(tid >> 6);
    const long m0 = (long)blockIdx.x * 128;
    const long n0 = (long)blockIdx.y * 128;
    const int wr = wid >> 1, wc = wid & 1;
    const int r0 = wid * 32;
    const int lrow = lane >> 2;
    const int lkb = (lane & 3) * 8;
    const u16* gA = A + (m0 + r0 + lrow) * (long)K + lkb;
    const u16* gB = Bt + (n0 + r0 + lrow) * (long)K + lkb;
    u16* lA = &aLds[r0 * 32];
    u16* lB = &bLds[r0 * 32];
    f32x4 acc[4][4] = {};
    const int fr = lane & 15, fk = (lane >> 4) * 8;
    for (int kt = 0; kt < K; kt += 32) {
        gload16(gA + kt, lA);
        gload16(gA + kt + 16 * (long)K, lA + 16 * 32);
        gload16(gB + kt, lB);
        gload16(gB + kt + 16 * (long)K, lB + 16 * 32);
        __syncthreads();
        bf16x8 af[4], bfr[4];
#pragma unroll
        for (int i = 0; i < 4; i++) {
            af[i] = *(const bf16x8*)&aLds[(wr * 64 + i * 16 + fr) * 32 + fk];
            bfr[i] = *(const bf16x8*)&bLds[(wc * 64 + i * 16 + fr) * 32 + fk];
        }
#pragma unroll
        for (int i = 0; i < 4; i++)
#pragma unroll
            for (int j = 0; j < 4; j++)
                acc[i][j] = __builtin_amdgcn_mfma_f32_16x16x32_bf16(af[i], bfr[j], acc[i][j], 0, 0, 0);
        __syncthreads();
    }
    const int orow = (lane >> 4) * 4, ocol = lane & 15;
#pragma unroll
    for (int i = 0; i < 4; i++)
#pragma unroll
        for (int j = 0; j < 4; j++) {
            long r = m0 + wr * 64 + i * 16 + orow;
            long c = n0 + wc * 64 + j * 16 + ocol;
#pragma unroll
            for (int t = 0; t < 4; t++) {
                if (F32OUT)
                    ((float*)Cout)[(r + t) * N + c] = acc[i][j][t];
                else
                    ((u16*)Cout)[(r + t) * N + c] = f2bf(acc[i][j][t]);
            }
        }
}

// ---------------- flash attention: 1 wave/block, QBLK=32, KVBLK=32, causal ----------------
__global__ __launch_bounds__(64) void attn_k(const u16* __restrict__ q, const u16* __restrict__ k,
                                             const u16* __restrict__ vt, u16* __restrict__ o) {
    const int lane = threadIdx.x;
    const int qt = blockIdx.x, h = blockIdx.y, b = blockIdx.z;
    const int kv = h >> 2;
    const int q0 = qt * 32;
    const int fr = lane & 15, kg = lane >> 4;
    const long HD = (long)Hh * Dd;
    const long KD = (long)KVh * Dd;
    const long qbase = ((long)(b * Tt + q0)) * HD + (long)h * Dd;
    const long kbase = ((long)(b * Tt)) * KD + (long)kv * Dd;
    const long vbase = ((long)(b * KVh + kv)) * Dd * Tt;

    bf16x8 qa[2][4];
#pragma unroll
    for (int qi = 0; qi < 2; qi++)
#pragma unroll
        for (int kc = 0; kc < 4; kc++)
            qa[qi][kc] = *(const bf16x8*)&q[qbase + (long)(qi * 16 + fr) * HD + kc * 32 + kg * 8];

    f32x4 oa[2][8] = {};
    float mr[2][4], lr[2][4];
#pragma unroll
    for (int qi = 0; qi < 2; qi++)
#pragma unroll
        for (int r = 0; r < 4; r++) { mr[qi][r] = -1e30f; lr[qi][r] = 0.0f; }

    __shared__ u16 pl[2][16][40];

    const int ntiles = qt + 1;
    for (int it = 0; it < ntiles; ++it) {
        const int s0 = it * 32;
        bf16x8 kb[2][4];
#pragma unroll
        for (int cg = 0; cg < 2; cg++)
#pragma unroll
            for (int kc = 0; kc < 4; kc++)
                kb[cg][kc] = *(const bf16x8*)&k[kbase + (long)(s0 + cg * 16 + fr) * KD + kc * 32 + kg * 8];
#pragma unroll
        for (int qi = 0; qi < 2; qi++) {
            f32x4 sc0 = {0.f, 0.f, 0.f, 0.f}, sc1 = {0.f, 0.f, 0.f, 0.f};
#pragma unroll
            for (int kc = 0; kc < 4; kc++) {
                sc0 = __builtin_amdgcn_mfma_f32_16x16x32_bf16(qa[qi][kc], kb[0][kc], sc0, 0, 0, 0);
                sc1 = __builtin_amdgcn_mfma_f32_16x16x32_bf16(qa[qi][kc], kb[1][kc], sc1, 0, 0, 0);
            }
            if (it == ntiles - 1) {
#pragma unroll
                for (int r = 0; r < 4; r++) {
                    int qq = q0 + qi * 16 + kg * 4 + r;
                    if (s0 + fr > qq) sc0[r] = -1e30f;
                    if (s0 + 16 + fr > qq) sc1[r] = -1e30f;
                }
            }
#pragma unroll
            for (int r = 0; r < 4; r++) {
                float tm = fmaxf(sc0[r], sc1[r]);
                tm = fmaxf(tm, __shfl_xor(tm, 1));
                tm = fmaxf(tm, __shfl_xor(tm, 2));
                tm = fmaxf(tm, __shfl_xor(tm, 4));
                tm = fmaxf(tm, __shfl_xor(tm, 8));
                float mn = fmaxf(mr[qi][r], tm);
                float al = __expf(mr[qi][r] - mn);
                float p0 = __expf(sc0[r] - mn);
                float p1 = __expf(sc1[r] - mn);
                float rs = p0 + p1;
                rs += __shfl_xor(rs, 1);
                rs += __shfl_xor(rs, 2);
                rs += __shfl_xor(rs, 4);
                rs += __shfl_xor(rs, 8);
                lr[qi][r] = lr[qi][r] * al + rs;
                mr[qi][r] = mn;
#pragma unroll
                for (int dc = 0; dc < 8; dc++) oa[qi][dc][r] *= al;
                pl[qi][kg * 4 + r][fr] = f2bf(p0);
                pl[qi][kg * 4 + r][16 + fr] = f2bf(p1);
            }
        }
        __syncthreads();
        bf16x8 pa0 = *(const bf16x8*)&pl[0][fr][kg * 8];
        bf16x8 pa1 = *(const bf16x8*)&pl[1][fr][kg * 8];
#pragma unroll
        for (int dc = 0; dc < 8; dc++) {
            bf16x8 vb = *(const bf16x8*)&vt[vbase + (long)(dc * 16 + fr) * Tt + s0 + kg * 8];
            oa[0][dc] = __builtin_amdgcn_mfma_f32_16x16x32_bf16(pa0, vb, oa[0][dc], 0, 0, 0);
            oa[1][dc] = __builtin_amdgcn_mfma_f32_16x16x32_bf16(pa1, vb, oa[1][dc], 0, 0, 0);
        }
        __syncthreads();
    }
#pragma unroll
    for (int qi = 0; qi < 2; qi++)
#pragma unroll
        for (int dc = 0; dc < 8; dc++)
#pragma unroll
            for (int r = 0; r < 4; r++) {
                float val = oa[qi][dc][r] / lr[qi][r];
                o[qbase + (long)(qi * 16 + kg * 4 + r) * HD + dc * 16 + fr] = f2bf(val);
            }
}

extern "C" void kernel_launch(void* const* d_in, const int* in_sizes, int n_in,
                              void* d_out, int out_size, void* d_ws, size_t ws_size,
                              hipStream_t stream) {
    (void)in_sizes; (void)n_in; (void)out_size; (void)ws_size;
    const float* x = (const float*)d_in[0];
    const float* Wq = (const float*)d_in[1];
    const float* Wk = (const float*)d_in[2];
    const float* Wv = (const float*)d_in[3];
    const float* Wo = (const float*)d_in[4];

    char* ws = (char*)d_ws;
    u16* xb   = (u16*)(ws + 0);            // 33.5MB  (b,t,c) bf16; later reused as attn output (b,t,h,d)
    u16* kbuf = (u16*)(ws + 33554432);     // 8.4MB   (b,t,kv,d)
    u16* vbuf = (u16*)(ws + 41943040);     // 8.4MB   (b,t,kv,d)
    u16* vtb  = (u16*)(ws + 50331648);     // 8.4MB   (b,kv,d,t)
    u16* wqt  = (u16*)(ws + 58720256);     // 8.4MB
    u16* wkt  = (u16*)(ws + 67108864);     // 2.1MB
    u16* wvt  = (u16*)(ws + 69206016);     // 2.1MB
    u16* wot  = (u16*)(ws + 71303168);     // 8.4MB
    float* cosb = (float*)(ws + 79691776); // 0.5MB
    float* sinb = (float*)(ws + 80216064); // 0.5MB
    u16* qbuf = (u16*)d_out;               // q (b,t,h,d) bf16 lives in d_out until final GEMM

    dim3 tb(32, 8);
    cast_k<<<16384, 256, 0, stream>>>(x, xb, 4194304);
    twt_k<<<dim3(64, 64), tb, 0, stream>>>(Wq, wqt, 2048, 2048);
    twt_k<<<dim3(16, 64), tb, 0, stream>>>(Wk, wkt, 2048, 512);
    twt_k<<<dim3(16, 64), tb, 0, stream>>>(Wv, wvt, 2048, 512);
    twt_k<<<dim3(64, 64), tb, 0, stream>>>(Wo, wot, 2048, 2048);
    tables_k<<<512, 256, 0, stream>>>(cosb, sinb);

    gemm_k<0><<<dim3(64, 16), 256, 0, stream>>>(xb, wqt, qbuf, 8192, 2048, 2048);
    gemm_k<0><<<dim3(64, 4), 256, 0, stream>>>(xb, wkt, kbuf, 8192, 512, 2048);
    gemm_k<0><<<dim3(64, 4), 256, 0, stream>>>(xb, wvt, vbuf, 8192, 512, 2048);

    rope_k<<<32768, 256, 0, stream>>>(qbuf, cosb, sinb, 16, 0.08838834764831845f, 8388608);
    rope_k<<<8192, 256, 0, stream>>>(kbuf, cosb, sinb, 4, 1.0f, 2097152);
    tv_k<<<dim3(4, 64, 16), tb, 0, stream>>>(vbuf, vtb);

    attn_k<<<dim3(64, 16, 4), 64, 0, stream>>>(qbuf, kbuf, vtb, xb);

    gemm_k<1><<<dim3(64, 16), 256, 0, stream>>>(xb, wot, d_out, 8192, 2048, 2048);
}

// Round 2
// 622.128 us; speedup vs baseline: 1.2911x; 1.2911x over previous
//
#include <hip/hip_runtime.h>
#include <cstdint>

#define DEV __device__ __forceinline__

typedef __attribute__((ext_vector_type(4))) float f32x4;
typedef __attribute__((ext_vector_type(4))) float float4v;
typedef __attribute__((ext_vector_type(8))) short bf16x8;
typedef __attribute__((ext_vector_type(4))) unsigned short ushort4v;
typedef unsigned short u16;

static constexpr int Bb = 4, Tt = 2048, Hh = 16, KVh = 4, Dd = 128;

DEV u16 f2bf(float x) {
    union { float f; unsigned u; } v; v.f = x;
    unsigned r = v.u + 0x7FFF + ((v.u >> 16) & 1);
    return (u16)(r >> 16);
}
DEV float bf2f(u16 b) {
    union { unsigned u; float f; } v; v.u = ((unsigned)b) << 16;
    return v.f;
}

typedef const void __attribute__((address_space(1)))* gas1;
typedef void __attribute__((address_space(3)))* las3;
DEV void gload16(const void* g, void* l) {
    __builtin_amdgcn_global_load_lds((gas1)g, (las3)l, 16, 0, 0);
}

// ---------------- cast x -> bf16 ----------------
__global__ __launch_bounds__(256) void cast_k(const float* __restrict__ x, u16* __restrict__ xb, long n4) {
    long id = (long)blockIdx.x * 256 + threadIdx.x;
    if (id >= n4) return;
    float4v v = *(const float4v*)&x[id * 4];
    ushort4v o;
    o[0] = f2bf(v[0]); o[1] = f2bf(v[1]); o[2] = f2bf(v[2]); o[3] = f2bf(v[3]);
    *(ushort4v*)&xb[id * 4] = o;
}

// ---------------- transpose+cast weight: W (K x N) f32 -> Wt (N x K) bf16 ----------------
__global__ __launch_bounds__(256) void twt_k(const float* __restrict__ W, u16* __restrict__ Wt, int K, int N) {
    __shared__ float tile[32][33];
    int tx = threadIdx.x, ty = threadIdx.y;
    long n0 = (long)blockIdx.x * 32, k0 = (long)blockIdx.y * 32;
#pragma unroll
    for (int j = 0; j < 4; j++)
        tile[ty + j * 8][tx] = W[(k0 + ty + j * 8) * (long)N + n0 + tx];
    __syncthreads();
#pragma unroll
    for (int j = 0; j < 4; j++)
        Wt[(n0 + ty + j * 8) * (long)K + k0 + tx] = f2bf(tile[tx][ty + j * 8]);
}

// ---------------- transpose v (b,t,kv,d) -> vt (b,kv,d,t) ----------------
__global__ __launch_bounds__(256) void tv_k(const u16* __restrict__ v, u16* __restrict__ vt) {
    __shared__ u16 tile[32][33];
    int tx = threadIdx.x, ty = threadIdx.y;
    int d0 = blockIdx.x * 32;
    int t0 = blockIdx.y * 32;
    int bk = blockIdx.z;
    int b = bk >> 2, kv = bk & 3;
#pragma unroll
    for (int j = 0; j < 4; j++)
        tile[ty + j * 8][tx] = v[((long)(b * Tt + t0 + ty + j * 8) * KVh + kv) * Dd + d0 + tx];
    __syncthreads();
#pragma unroll
    for (int j = 0; j < 4; j++)
        vt[((long)(b * KVh + kv) * Dd + d0 + ty + j * 8) * Tt + t0 + tx] = tile[tx][ty + j * 8];
}

// ---------------- rope tables: [t][i], i<64 ----------------
__global__ __launch_bounds__(256) void tables_k(float* __restrict__ cosb, float* __restrict__ sinb) {
    int id = blockIdx.x * 256 + threadIdx.x; // < 2048*64
    int t = id >> 6, i = id & 63;
    float inv = powf(10000.0f, -(float)i * (1.0f / 64.0f));
    float f = (float)t * inv;
    cosb[id] = cosf(f);
    sinb[id] = sinf(f);
}

// ---------------- rope in-place on (b,t,nh,128); scale folded for q ----------------
__global__ __launch_bounds__(256) void rope_k(u16* __restrict__ p, const float* __restrict__ cosb,
                                              const float* __restrict__ sinb, int nh, float scale, int total) {
    int id = blockIdx.x * 256 + threadIdx.x;
    if (id >= total) return;
    int i = id & 63;
    int bth = id >> 6;
    int t = (bth / nh) % Tt;
    u16* ptr = p + (long)bth * Dd;
    float x1 = bf2f(ptr[i]), x2 = bf2f(ptr[i + 64]);
    float c = cosb[t * 64 + i], s = sinb[t * 64 + i];
    ptr[i] = f2bf((x1 * c - x2 * s) * scale);
    ptr[i + 64] = f2bf((x2 * c + x1 * s) * scale);
}

// ---------------- GEMM: A (M x K) bf16 row-major, Bt (N x K) bf16 row-major -> C (M x N) ----------------
template <int F32OUT>
__global__ __launch_bounds__(256) void gemm_k(const u16* __restrict__ A, const u16* __restrict__ Bt,
                                              void* __restrict__ Cout, int M, int N, int K) {
    __shared__ u16 aLds[128 * 32];
    __shared__ u16 bLds[128 * 32];
    const int tid = threadIdx.x;
    const int lane = tid & 63;
    const int wid = __builtin_amdgcn_readfirstlane(tid >> 6);
    const long m0 = (long)blockIdx.x * 128;
    const long n0 = (long)blockIdx.y * 128;
    const int wr = wid >> 1, wc = wid & 1;
    const int r0 = wid * 32;
    const int lrow = lane >> 2;
    const int lkb = (lane & 3) * 8;
    const u16* gA = A + (m0 + r0 + lrow) * (long)K + lkb;
    const u16* gB = Bt + (n0 + r0 + lrow) * (long)K + lkb;
    u16* lA = &aLds[r0 * 32];
    u16* lB = &bLds[r0 * 32];
    f32x4 acc[4][4] = {};
    const int fr = lane & 15, fk = (lane >> 4) * 8;
    for (int kt = 0; kt < K; kt += 32) {
        gload16(gA + kt, lA);
        gload16(gA + kt + 16 * (long)K, lA + 16 * 32);
        gload16(gB + kt, lB);
        gload16(gB + kt + 16 * (long)K, lB + 16 * 32);
        __syncthreads();
        bf16x8 af[4], bfr[4];
#pragma unroll
        for (int i = 0; i < 4; i++) {
            af[i] = *(const bf16x8*)&aLds[(wr * 64 + i * 16 + fr) * 32 + fk];
            bfr[i] = *(const bf16x8*)&bLds[(wc * 64 + i * 16 + fr) * 32 + fk];
        }
#pragma unroll
        for (int i = 0; i < 4; i++)
#pragma unroll
            for (int j = 0; j < 4; j++)
                acc[i][j] = __builtin_amdgcn_mfma_f32_16x16x32_bf16(af[i], bfr[j], acc[i][j], 0, 0, 0);
        __syncthreads();
    }
    const int orow = (lane >> 4) * 4, ocol = lane & 15;
#pragma unroll
    for (int i = 0; i < 4; i++)
#pragma unroll
        for (int j = 0; j < 4; j++) {
            long r = m0 + wr * 64 + i * 16 + orow;
            long c = n0 + wc * 64 + j * 16 + ocol;
#pragma unroll
            for (int t = 0; t < 4; t++) {
                if (F32OUT)
                    ((float*)Cout)[(r + t) * N + c] = acc[i][j][t];
                else
                    ((u16*)Cout)[(r + t) * N + c] = f2bf(acc[i][j][t]);
            }
        }
}

// ---------------- flash attention v2: 4 waves/block, QBLK=128 (32/wave), KVBLK=64, dbuf LDS ----------------
__global__ __launch_bounds__(256, 2) void attn_k(const u16* __restrict__ q, const u16* __restrict__ k,
                                                 const u16* __restrict__ vt, u16* __restrict__ o) {
    __shared__ u16 kl[2][64 * 128];   // K tile, XOR-swizzled (c16 ^= row&7)
    __shared__ u16 vl[2][128 * 64];   // V^T tile, XOR-swizzled
    __shared__ u16 pl[4][2][16][40];  // per-wave P staging
    const int tid = threadIdx.x;
    const int lane = tid & 63;
    const int w = tid >> 6;
    const int qb = 15 - blockIdx.x;   // big causal blocks dispatch first
    const int h = blockIdx.y, b = blockIdx.z;
    const int kv = h >> 2;
    const int q0w = qb * 128 + w * 32;
    const int fr = lane & 15, kg = lane >> 4;
    const long HD = (long)Hh * Dd;
    const long KD = (long)KVh * Dd;
    const long qbase = ((long)(b * Tt + q0w)) * HD + (long)h * Dd;
    const long kbase = ((long)(b * Tt)) * KD + (long)kv * Dd;
    const long vbase = ((long)(b * KVh + kv)) * (long)Dd * Tt;

    bf16x8 qa[2][4];
#pragma unroll
    for (int qi = 0; qi < 2; qi++)
#pragma unroll
        for (int kc = 0; kc < 4; kc++)
            qa[qi][kc] = *(const bf16x8*)&q[qbase + (long)(qi * 16 + fr) * HD + kc * 32 + kg * 8];

    f32x4 oa[2][8] = {};
    float mr[2][4], lr[2][4];
#pragma unroll
    for (int qi = 0; qi < 2; qi++)
#pragma unroll
        for (int r = 0; r < 4; r++) { mr[qi][r] = -1e30f; lr[qi][r] = 0.0f; }

    const int nt = qb * 2 + 2;

    // cooperative staging: per wave, 4 x 1KB issues each for K and V
    auto stage = [&](int bb, int it) {
        const int s0 = it * 64;
#pragma unroll
        for (int i = 0; i < 4; i++) {
            int c = (w * 4 + i) * 64 + lane;
            int row = c >> 4;
            int c16 = (c & 15) ^ (row & 7);
            gload16(k + kbase + (long)(s0 + row) * KD + c16 * 8, &kl[bb][(w * 4 + i) * 512]);
        }
#pragma unroll
        for (int i = 0; i < 4; i++) {
            int c = (w * 4 + i) * 64 + lane;
            int row = c >> 3;
            int c16 = (c & 7) ^ (row & 7);
            gload16(vt + vbase + (long)row * Tt + s0 + c16 * 8, &vl[bb][(w * 4 + i) * 512]);
        }
    };

    stage(0, 0);
    __syncthreads();
    int cur = 0;
    for (int it = 0; it < nt; ++it) {
        if (it + 1 < nt) stage(cur ^ 1, it + 1);
        const int s0 = it * 64;
        if (s0 <= q0w + 31) {
            // ---- QK^T ----
            f32x4 sc[2][4] = {};
            __builtin_amdgcn_s_setprio(1);
#pragma unroll
            for (int cg = 0; cg < 4; cg++) {
                bf16x8 kb[4];
#pragma unroll
                for (int kc = 0; kc < 4; kc++) {
                    int row = cg * 16 + fr;
                    kb[kc] = *(const bf16x8*)&kl[cur][row * 128 + (((kc * 4 + kg) ^ (row & 7)) * 8)];
                }
#pragma unroll
                for (int kc = 0; kc < 4; kc++) {
                    sc[0][cg] = __builtin_amdgcn_mfma_f32_16x16x32_bf16(qa[0][kc], kb[kc], sc[0][cg], 0, 0, 0);
                    sc[1][cg] = __builtin_amdgcn_mfma_f32_16x16x32_bf16(qa[1][kc], kb[kc], sc[1][cg], 0, 0, 0);
                }
            }
            __builtin_amdgcn_s_setprio(0);
            // ---- causal mask ----
            if (s0 + 63 > q0w) {
#pragma unroll
                for (int qi = 0; qi < 2; qi++)
#pragma unroll
                    for (int cg = 0; cg < 4; cg++)
#pragma unroll
                        for (int r = 0; r < 4; r++) {
                            int qq = q0w + qi * 16 + kg * 4 + r;
                            if (s0 + cg * 16 + fr > qq) sc[qi][cg][r] = -1e30f;
                        }
            }
            // ---- online softmax ----
#pragma unroll
            for (int qi = 0; qi < 2; qi++)
#pragma unroll
                for (int r = 0; r < 4; r++) {
                    float tm = fmaxf(fmaxf(sc[qi][0][r], sc[qi][1][r]),
                                     fmaxf(sc[qi][2][r], sc[qi][3][r]));
                    tm = fmaxf(tm, __shfl_xor(tm, 1));
                    tm = fmaxf(tm, __shfl_xor(tm, 2));
                    tm = fmaxf(tm, __shfl_xor(tm, 4));
                    tm = fmaxf(tm, __shfl_xor(tm, 8));
                    float mn = fmaxf(mr[qi][r], tm);
                    float al = __expf(mr[qi][r] - mn);
                    float p0 = __expf(sc[qi][0][r] - mn);
                    float p1 = __expf(sc[qi][1][r] - mn);
                    float p2 = __expf(sc[qi][2][r] - mn);
                    float p3 = __expf(sc[qi][3][r] - mn);
                    sc[qi][0][r] = p0; sc[qi][1][r] = p1; sc[qi][2][r] = p2; sc[qi][3][r] = p3;
                    float rs = (p0 + p1) + (p2 + p3);
                    rs += __shfl_xor(rs, 1);
                    rs += __shfl_xor(rs, 2);
                    rs += __shfl_xor(rs, 4);
                    rs += __shfl_xor(rs, 8);
                    lr[qi][r] = lr[qi][r] * al + rs;
                    mr[qi][r] = mn;
#pragma unroll
                    for (int dc = 0; dc < 8; dc++) oa[qi][dc][r] *= al;
                }
            // ---- PV in two k-slices (pl buffer reused) ----
#pragma unroll
            for (int ks = 0; ks < 2; ks++) {
#pragma unroll
                for (int qi = 0; qi < 2; qi++)
#pragma unroll
                    for (int r = 0; r < 4; r++) {
                        pl[w][qi][kg * 4 + r][fr] = f2bf(sc[qi][ks * 2][r]);
                        pl[w][qi][kg * 4 + r][16 + fr] = f2bf(sc[qi][ks * 2 + 1][r]);
                    }
                bf16x8 pa0 = *(const bf16x8*)&pl[w][0][fr][kg * 8];
                bf16x8 pa1 = *(const bf16x8*)&pl[w][1][fr][kg * 8];
                __builtin_amdgcn_s_setprio(1);
#pragma unroll
                for (int dc = 0; dc < 8; dc++) {
                    int row = dc * 16 + fr;
                    bf16x8 vb = *(const bf16x8*)&vl[cur][row * 64 + (((ks * 4 + kg) ^ (row & 7)) * 8)];
                    oa[0][dc] = __builtin_amdgcn_mfma_f32_16x16x32_bf16(pa0, vb, oa[0][dc], 0, 0, 0);
                    oa[1][dc] = __builtin_amdgcn_mfma_f32_16x16x32_bf16(pa1, vb, oa[1][dc], 0, 0, 0);
                }
                __builtin_amdgcn_s_setprio(0);
            }
        }
        __syncthreads();
        cur ^= 1;
    }
#pragma unroll
    for (int qi = 0; qi < 2; qi++)
#pragma unroll
        for (int dc = 0; dc < 8; dc++)
#pragma unroll
            for (int r = 0; r < 4; r++) {
                float val = oa[qi][dc][r] / lr[qi][r];
                o[qbase + (long)(qi * 16 + kg * 4 + r) * HD + dc * 16 + fr] = f2bf(val);
            }
}

extern "C" void kernel_launch(void* const* d_in, const int* in_sizes, int n_in,
                              void* d_out, int out_size, void* d_ws, size_t ws_size,
                              hipStream_t stream) {
    (void)in_sizes; (void)n_in; (void)out_size; (void)ws_size;
    const float* x = (const float*)d_in[0];
    const float* Wq = (const float*)d_in[1];
    const float* Wk = (const float*)d_in[2];
    const float* Wv = (const float*)d_in[3];
    const float* Wo = (const float*)d_in[4];

    char* ws = (char*)d_ws;
    u16* xb   = (u16*)(ws + 0);            // 33.5MB  (b,t,c) bf16; later reused as attn output (b,t,h,d)
    u16* kbuf = (u16*)(ws + 33554432);     // 8.4MB   (b,t,kv,d)
    u16* vbuf = (u16*)(ws + 41943040);     // 8.4MB   (b,t,kv,d)
    u16* vtb  = (u16*)(ws + 50331648);     // 8.4MB   (b,kv,d,t)
    u16* wqt  = (u16*)(ws + 58720256);     // 8.4MB
    u16* wkt  = (u16*)(ws + 67108864);     // 2.1MB
    u16* wvt  = (u16*)(ws + 69206016);     // 2.1MB
    u16* wot  = (u16*)(ws + 71303168);     // 8.4MB
    float* cosb = (float*)(ws + 79691776); // 0.5MB
    float* sinb = (float*)(ws + 80216064); // 0.5MB
    u16* qbuf = (u16*)d_out;               // q (b,t,h,d) bf16 lives in d_out until final GEMM

    dim3 tb(32, 8);
    cast_k<<<16384, 256, 0, stream>>>(x, xb, 4194304);
    twt_k<<<dim3(64, 64), tb, 0, stream>>>(Wq, wqt, 2048, 2048);
    twt_k<<<dim3(16, 64), tb, 0, stream>>>(Wk, wkt, 2048, 512);
    twt_k<<<dim3(16, 64), tb, 0, stream>>>(Wv, wvt, 2048, 512);
    twt_k<<<dim3(64, 64), tb, 0, stream>>>(Wo, wot, 2048, 2048);
    tables_k<<<512, 256, 0, stream>>>(cosb, sinb);

    gemm_k<0><<<dim3(64, 16), 256, 0, stream>>>(xb, wqt, qbuf, 8192, 2048, 2048);
    gemm_k<0><<<dim3(64, 4), 256, 0, stream>>>(xb, wkt, kbuf, 8192, 512, 2048);
    gemm_k<0><<<dim3(64, 4), 256, 0, stream>>>(xb, wvt, vbuf, 8192, 512, 2048);

    rope_k<<<32768, 256, 0, stream>>>(qbuf, cosb, sinb, 16, 0.08838834764831845f, 8388608);
    rope_k<<<8192, 256, 0, stream>>>(kbuf, cosb, sinb, 4, 1.0f, 2097152);
    tv_k<<<dim3(4, 64, 16), tb, 0, stream>>>(vbuf, vtb);

    attn_k<<<dim3(16, 16, 4), 256, 0, stream>>>(qbuf, kbuf, vtb, xb);

    gemm_k<1><<<dim3(64, 16), 256, 0, stream>>>(xb, wot, d_out, 8192, 2048, 2048);
}